// Round 12
// baseline (975.776 us; speedup 1.0000x reference)
//
#include <hip/hip_runtime.h>
#include <cstddef>

#define NROWS 16384
#define NE    8192
#define DD    256

typedef unsigned long long u64;
typedef float vf4 __attribute__((ext_vector_type(4)));
typedef short bf16x8 __attribute__((ext_vector_type(8)));
typedef float f32x4 __attribute__((ext_vector_type(4)));
typedef unsigned short us8 __attribute__((ext_vector_type(8)));

#define OH_TOT ((size_t)NROWS * NE)           // 134217728 floats
#define OH_VEC ((OH_TOT - 4) / 4)             // 33554431 aligned vf4 slots
#define CAND_CAP 4000000
#define LLIST_CAP 2048

// ---------------------------------------------------------------------------
// k_rowsq: zsq/esq in numpy pairwise order (bit-exact). For emb rows, ALSO
// writes ebf: bf16 emb in MFMA-fragment-major order (coalesced screen loads):
//   slot (tile*8 + kt)*64 + kq*16 + (col&15) holds eb[col][kt*32+kq*8 ..+7]
// wadd = rigorous screen window (validated rounds 6-11):
//   2*( (zsq+2)*1.2e-7 + 2*(1e-6*Ssum) + 5e-8 )
// Inits best[], counts, cand_n.
// ---------------------------------------------------------------------------
__global__ __launch_bounds__(256) void k_rowsq(
    const float* __restrict__ z, const float* __restrict__ emb,
    float* __restrict__ zsq, float* __restrict__ esq,
    u64* __restrict__ best, int* __restrict__ counts,
    float* __restrict__ wadd, int* __restrict__ cand_n,
    unsigned short* __restrict__ ebf)
{
  const int g = blockIdx.x * 256 + threadIdx.x;   // 0 .. 24575
  if (g == 0) *cand_n = 0;
  if (g < NE) counts[g] = 0;
  if (g < NROWS) best[g] = ~0ull;

  const float* row;
  float* outp;
  if (g < NROWS) { row = z + (size_t)g * DD;            outp = zsq + g; }
  else           { row = emb + (size_t)(g - NROWS) * DD; outp = esq + (g - NROWS); }

  float sa = 0.0f;
  float half_s[2];
#pragma unroll
  for (int h = 0; h < 2; ++h) {
    const float* p = row + h * 128;
    float r[8];
    {
      const float4 v0 = *(const float4*)(p);
      const float4 v1 = *(const float4*)(p + 4);
      const float xs[8] = {v0.x, v0.y, v0.z, v0.w, v1.x, v1.y, v1.z, v1.w};
#pragma unroll
      for (int j = 0; j < 8; ++j) {
        float sq = xs[j] * xs[j];
        asm volatile("" : "+v"(sq));   // np rounds x*x before the add chain
        r[j] = sq;
        sa += fabsf(xs[j]);
      }
    }
    for (int i = 8; i < 128; i += 8) {
      const float4 v0 = *(const float4*)(p + i);
      const float4 v1 = *(const float4*)(p + i + 4);
      const float xs[8] = {v0.x, v0.y, v0.z, v0.w, v1.x, v1.y, v1.z, v1.w};
#pragma unroll
      for (int j = 0; j < 8; ++j) {
        float sq = xs[j] * xs[j];
        asm volatile("" : "+v"(sq));
        r[j] = r[j] + sq;
        sa += fabsf(xs[j]);
      }
    }
    half_s[h] = ((r[0] + r[1]) + (r[2] + r[3])) + ((r[4] + r[5]) + (r[6] + r[7]));
  }
  const float zs = half_s[0] + half_s[1];
  *outp = zs;
  if (g < NROWS) {
    wadd[g] = 2.0f * ((zs + 2.0f) * 1.2e-7f + 2.0f * (1.0e-6f * sa) + 5.0e-8f);
  } else {
    const int c = g - NROWS;
    const int t = c >> 4, l = c & 15;
#pragma unroll
    for (int kt = 0; kt < 8; ++kt) {
#pragma unroll
      for (int kq = 0; kq < 4; ++kq) {
        const float4 v0 = *(const float4*)(row + kt * 32 + kq * 8);
        const float4 v1 = *(const float4*)(row + kt * 32 + kq * 8 + 4);
        const float xs[8] = {v0.x, v0.y, v0.z, v0.w, v1.x, v1.y, v1.z, v1.w};
        us8 u;
#pragma unroll
        for (int j = 0; j < 8; ++j) {
          const unsigned b = __float_as_uint(xs[j]);
          u[j] = (unsigned short)((b + 0x7FFFu + ((b >> 16) & 1u)) >> 16);
        }
        *(us8*)(ebf + (((size_t)(t * 8 + kt)) * 64 + kq * 16 + l) * 8) = u;
      }
    }
  }
}

__device__ __forceinline__ unsigned short f2bf_rne(float f) {
  const unsigned u = __float_as_uint(f);
  return (unsigned short)((u + 0x7FFFu + ((u >> 16) & 1u)) >> 16);
}
__device__ __forceinline__ unsigned encf(float f) {
  const unsigned u = __float_as_uint(f);
  return (u & 0x80000000u) ? ~u : (u | 0x80000000u);
}
__device__ __forceinline__ float decf(unsigned k) {
  const unsigned u = (k & 0x80000000u) ? (k ^ 0x80000000u) : ~k;
  return __uint_as_float(u);
}

// ---------------------------------------------------------------------------
// k_screen v6: two-phase MFMA screen, 32 rows/wave (2 A-frag sets) so each
// 8-load B tile feeds 16 MFMAs (2x the A-reuse of v5, half the L2 traffic,
// 4 independent MFMA chains). No waves_per_eu attribute EVER (rounds 4/10:
// any value clamps the allocator into operand spill).
//   1024 blocks x 256 thr (4 blocks/CU target); block = 128 rows x 1024 cols
//   (one col-eighth, XCD-aligned: 0.5 MB ebf slice per XCD L2). B-frags via
//   coalesced 1-KB wave-loads from fragment-major ebf, single-buffered.
//   Phase 1: min-only sweep (64 tiles) -> smin (LDS atomicMin) -> barrier ->
//   final per-row thresholds (eighth-local min + wadd: the global argmin col
//   always qualifies in its own eighth -- same proof as quarters, r7-r11).
//   Phase 2: re-sweep, emit rv <= thr into LDS list -> one global flush.
//   One-hot zero-fill fused as END burst (round-9-validated: stores never
//   precede loads -> no vmcnt pollution; overlaps straggler compute).
// ---------------------------------------------------------------------------
__global__ __launch_bounds__(256) void k_screen(
    const float* __restrict__ z, const unsigned short* __restrict__ ebf,
    const float* __restrict__ esq, const float* __restrict__ wadd,
    unsigned* __restrict__ cand, int* __restrict__ cand_n,
    float* __restrict__ ohbase)
{
  __shared__ unsigned smin[128];
  __shared__ float wl[128];
  __shared__ unsigned llist[LLIST_CAP];
  __shared__ unsigned lcnt;
  __shared__ unsigned gbase;

  const int tid = threadIdx.x;
  const int b = blockIdx.x;                 // 0..1023
  const int eighth = b & 7;                 // XCD id -> col-eighth
  const int panel = b >> 3;                 // 0..127
  const int R0 = panel * 128;
  const int C0 = eighth * 1024;
  const int T0 = C0 >> 4;                   // 64 tiles per sweep

  const int wave = tid >> 6;                // rows R0 + wave*32 .. +31
  const int lane = tid & 63;
  const int l15 = lane & 15;
  const int kg = lane >> 4;

  if (tid < 128) { smin[tid] = 0xFFFFFFFFu; wl[tid] = wadd[R0 + tid]; }
  if (tid == 0) lcnt = 0;

  // two persistent A-frag sets: rows R0+wave*32+l15 (af0) and +16 (af1)
  bf16x8 af0[8], af1[8];
  {
    const float* zp0 = z + (size_t)(R0 + wave * 32 + l15) * DD + kg * 8;
    const float* zp1 = zp0 + 16 * DD;
#pragma unroll
    for (int kt = 0; kt < 8; ++kt) {
      const float4 a0 = *(const float4*)(zp0 + kt * 32);
      const float4 a1 = *(const float4*)(zp0 + kt * 32 + 4);
      const float4 c0 = *(const float4*)(zp1 + kt * 32);
      const float4 c1 = *(const float4*)(zp1 + kt * 32 + 4);
      bf16x8 w, v;
      w[0] = (short)f2bf_rne(a0.x); w[1] = (short)f2bf_rne(a0.y);
      w[2] = (short)f2bf_rne(a0.z); w[3] = (short)f2bf_rne(a0.w);
      w[4] = (short)f2bf_rne(a1.x); w[5] = (short)f2bf_rne(a1.y);
      w[6] = (short)f2bf_rne(a1.z); w[7] = (short)f2bf_rne(a1.w);
      v[0] = (short)f2bf_rne(c0.x); v[1] = (short)f2bf_rne(c0.y);
      v[2] = (short)f2bf_rne(c0.z); v[3] = (short)f2bf_rne(c0.w);
      v[4] = (short)f2bf_rne(c1.x); v[5] = (short)f2bf_rne(c1.y);
      v[6] = (short)f2bf_rne(c1.z); v[7] = (short)f2bf_rne(c1.w);
      af0[kt] = w;
      af1[kt] = v;
    }
  }
  __syncthreads();

  const int rbase = wave * 32 + kg * 4;     // af0 rows; af1 rows = rbase+16
  const bf16x8* fb = (const bf16x8*)ebf;

  // ---------------- phase 1: min-only sweep ----------------
  float rm[8];
#pragma unroll
  for (int i = 0; i < 8; ++i) rm[i] = 1e30f;
#pragma unroll 1
  for (int tt = 0; tt < 64; ++tt) {
    bf16x8 bfr[8];
#pragma unroll
    for (int kt = 0; kt < 8; ++kt)
      bfr[kt] = fb[(size_t)((T0 + tt) * 8 + kt) * 64 + lane];
    f32x4 e0 = (f32x4){0, 0, 0, 0}, o0 = (f32x4){0, 0, 0, 0};
    f32x4 e1 = (f32x4){0, 0, 0, 0}, o1 = (f32x4){0, 0, 0, 0};
#pragma unroll
    for (int kt = 0; kt < 8; kt += 2) {
      e0 = __builtin_amdgcn_mfma_f32_16x16x32_bf16(af0[kt], bfr[kt], e0, 0, 0, 0);
      o0 = __builtin_amdgcn_mfma_f32_16x16x32_bf16(af0[kt + 1], bfr[kt + 1], o0, 0, 0, 0);
      e1 = __builtin_amdgcn_mfma_f32_16x16x32_bf16(af1[kt], bfr[kt], e1, 0, 0, 0);
      o1 = __builtin_amdgcn_mfma_f32_16x16x32_bf16(af1[kt + 1], bfr[kt + 1], o1, 0, 0, 0);
    }
    const float ev = esq[C0 + tt * 16 + l15];
#pragma unroll
    for (int r = 0; r < 4; ++r) {
      rm[r]     = fminf(rm[r],     ev - 2.0f * (e0[r] + o0[r]));
      rm[4 + r] = fminf(rm[4 + r], ev - 2.0f * (e1[r] + o1[r]));
    }
  }
  // flush to smin
#pragma unroll
  for (int rs = 0; rs < 2; ++rs)
#pragma unroll
    for (int r = 0; r < 4; ++r) {
      float mn = rm[rs * 4 + r];
      mn = fminf(mn, __shfl_xor(mn, 1, 16));
      mn = fminf(mn, __shfl_xor(mn, 2, 16));
      mn = fminf(mn, __shfl_xor(mn, 4, 16));
      mn = fminf(mn, __shfl_xor(mn, 8, 16));
      if (l15 == 0) atomicMin(&smin[rbase + rs * 16 + r], encf(mn));
    }
  __syncthreads();

  float thr[8];
#pragma unroll
  for (int rs = 0; rs < 2; ++rs)
#pragma unroll
    for (int r = 0; r < 4; ++r) {
      const int R = rbase + rs * 16 + r;
      thr[rs * 4 + r] = decf(smin[R]) + wl[R];
    }

#define PUSH(E_)                                                            \
  {                                                                         \
    const unsigned s_ = atomicAdd(&lcnt, 1u);                               \
    if (s_ < LLIST_CAP) llist[s_] = (E_);                                   \
    else { const int g_ = atomicAdd(cand_n, 1);                             \
           if (g_ < CAND_CAP) cand[g_] = (E_); }                            \
  }

  // ---------------- phase 2: emission sweep (final thresholds) ------------
#pragma unroll 1
  for (int tt = 0; tt < 64; ++tt) {
    bf16x8 bfr[8];
#pragma unroll
    for (int kt = 0; kt < 8; ++kt)
      bfr[kt] = fb[(size_t)((T0 + tt) * 8 + kt) * 64 + lane];
    f32x4 e0 = (f32x4){0, 0, 0, 0}, o0 = (f32x4){0, 0, 0, 0};
    f32x4 e1 = (f32x4){0, 0, 0, 0}, o1 = (f32x4){0, 0, 0, 0};
#pragma unroll
    for (int kt = 0; kt < 8; kt += 2) {
      e0 = __builtin_amdgcn_mfma_f32_16x16x32_bf16(af0[kt], bfr[kt], e0, 0, 0, 0);
      o0 = __builtin_amdgcn_mfma_f32_16x16x32_bf16(af0[kt + 1], bfr[kt + 1], o0, 0, 0, 0);
      e1 = __builtin_amdgcn_mfma_f32_16x16x32_bf16(af1[kt], bfr[kt], e1, 0, 0, 0);
      o1 = __builtin_amdgcn_mfma_f32_16x16x32_bf16(af1[kt + 1], bfr[kt + 1], o1, 0, 0, 0);
    }
    const int c = C0 + tt * 16 + l15;
    const float ev = esq[c];
    float rv[8];
    float gm = 1e30f;
#pragma unroll
    for (int r = 0; r < 4; ++r) {
      rv[r]     = ev - 2.0f * (e0[r] + o0[r]);
      rv[4 + r] = ev - 2.0f * (e1[r] + o1[r]);
      gm = fminf(gm, rv[r] - thr[r]);
      gm = fminf(gm, rv[4 + r] - thr[4 + r]);
    }
    if (gm <= 0.0f) {
#pragma unroll
      for (int rs = 0; rs < 2; ++rs)
#pragma unroll
        for (int r = 0; r < 4; ++r)
          if (rv[rs * 4 + r] <= thr[rs * 4 + r])
            PUSH(((unsigned)(R0 + rbase + rs * 16 + r) << 13) | (unsigned)c);
    }
  }

  __syncthreads();
  const unsigned n = (lcnt < LLIST_CAP) ? lcnt : LLIST_CAP;
  if (tid == 0) gbase = (unsigned)atomicAdd(cand_n, (int)n);
  __syncthreads();
  for (unsigned i = tid; i < n; i += 256) {
    const unsigned g = gbase + i;
    if (g < CAND_CAP) cand[g] = llist[i];
  }

  // ---- one-hot zero-fill END burst (r9-validated placement) ----
  {
    const vf4 zz = {0.0f, 0.0f, 0.0f, 0.0f};
    float* zp = ohbase + 2;
    size_t zt = (size_t)b * 32768 + tid;
#pragma unroll 4
    for (int i = 0; i < 128; ++i) {
      if (zt < OH_VEC) __builtin_nontemporal_store(zz, (vf4*)(zp + 4 * zt));
      zt += 256;
    }
    if (b == 0 && tid == 0) { ohbase[0] = 0.0f; ohbase[1] = 0.0f; }
    if (b == 1023 && tid == 0) { ohbase[OH_TOT - 2] = 0.0f; ohbase[OH_TOT - 1] = 0.0f; }
  }
}

// ---------------------------------------------------------------------------
// k_recheck: exact fp32 chain (ascending-k fmaf, identical rounding to the
// reference) per candidate; u64-packed atomicMin -> exact argmin with
// np.argmin first-index tie-break.
// ---------------------------------------------------------------------------
__global__ __launch_bounds__(256) void k_recheck(
    const float* __restrict__ z, const float* __restrict__ emb,
    const float* __restrict__ zsq, const float* __restrict__ esq,
    const unsigned* __restrict__ cand, const int* __restrict__ cand_n,
    u64* __restrict__ best)
{
  const int n = min(*cand_n, CAND_CAP);
  for (int i = blockIdx.x * 256 + threadIdx.x; i < n; i += gridDim.x * 256) {
    const unsigned e = cand[i];
    const int row = (int)(e >> 13);
    const int col = (int)(e & (NE - 1));
    const float4* zr = (const float4*)(z + (size_t)row * DD);
    const float4* er = (const float4*)(emb + (size_t)col * DD);
    float dot = 0.0f;
#pragma unroll 8
    for (int q = 0; q < 64; ++q) {
      const float4 a = zr[q];
      const float4 b = er[q];
      dot = fmaf(a.x, b.x, dot);
      dot = fmaf(a.y, b.y, dot);
      dot = fmaf(a.z, b.z, dot);
      dot = fmaf(a.w, b.w, dot);
    }
    const float s1 = zsq[row] + esq[col];
    const float dv = s1 - 2.0f * dot;
    atomicMin(&best[row], ((u64)__float_as_uint(dv) << 32) | (unsigned)col);
  }
}

// ---------------------------------------------------------------------------
// k_gather2: 4 rows per block. z_q gather, one-hot 1.0 scatter (zeros laid
// down by k_screen's burst), float(index), counts, per-block loss partial.
// ---------------------------------------------------------------------------
__global__ __launch_bounds__(256) void k_gather2(
    const float* __restrict__ z, const float* __restrict__ emb,
    const u64* __restrict__ best,
    float* __restrict__ out_zq, float* __restrict__ out_onehot,
    float* __restrict__ out_idx, float* __restrict__ partials,
    int* __restrict__ counts)
{
  __shared__ float sred[256];
  const int row = blockIdx.x * 4 + (threadIdx.x >> 6);
  const int lane = threadIdx.x & 63;
  const int idx = (int)(unsigned)(best[row] & 0xffffffffull);
  const int k0 = lane * 4;

  const float4 e  = *(const float4*)(emb + (size_t)idx * DD + k0);
  const float4 zv = *(const float4*)(z + (size_t)row * DD + k0);
  *(float4*)(out_zq + (size_t)row * DD + k0) = e;

  const float dx = e.x - zv.x, dy = e.y - zv.y, dz = e.z - zv.z, dw = e.w - zv.w;
  sred[threadIdx.x] = dx * dx + dy * dy + dz * dz + dw * dw;

  if (lane == 0) {
    out_idx[row] = (float)idx;
    out_onehot[(size_t)row * NE + idx] = 1.0f;
    atomicAdd(&counts[idx], 1);
  }
  __syncthreads();
  for (int s = 128; s > 0; s >>= 1) {
    if (threadIdx.x < s) sred[threadIdx.x] += sred[threadIdx.x + s];
    __syncthreads();
  }
  if (threadIdx.x == 0) partials[blockIdx.x] = sred[0];
}

// ---------------------------------------------------------------------------
// k_final: loss = 1.25 * sum(partials) / (N*D); perplexity from counts.
// ---------------------------------------------------------------------------
__global__ __launch_bounds__(256) void k_final(
    const int* __restrict__ counts, const float* __restrict__ partials,
    float* __restrict__ out_loss, float* __restrict__ out_perp)
{
  __shared__ float sred[256];
  __shared__ float sl[256];
  float le = 0.0f;
  for (int e = threadIdx.x; e < NE; e += 256) {
    const float p = (float)counts[e] * (1.0f / 16384.0f);
    le += p * logf(p + 1e-10f);
  }
  float ll = 0.0f;
  for (int b = threadIdx.x; b < NROWS / 4; b += 256) ll += partials[b];
  sred[threadIdx.x] = le;
  sl[threadIdx.x] = ll;
  __syncthreads();
  for (int s = 128; s > 0; s >>= 1) {
    if (threadIdx.x < s) {
      sred[threadIdx.x] += sred[threadIdx.x + s];
      sl[threadIdx.x] += sl[threadIdx.x + s];
    }
    __syncthreads();
  }
  if (threadIdx.x == 0) {
    *out_perp = expf(-sred[0]);
    *out_loss = sl[0] * (1.25f / 4194304.0f);  // (1+beta) * sum / (N*D)
  }
}

// ---------------------------------------------------------------------------
// Output layout (float32, reference return order):
//   [0] loss | [1..4194304] z_q_st | [4194305] perplexity
//   [4194306..] one-hot | [138412034..] indices (as float)
// Workspace (floats): zsq 16K | esq 8K | best 32K | counts 8K | partials 4K |
//   wadd 16K | cand_n+pad | ebf (bf16 fragment-major, 1M floats) | cand 16MB
// (bulk intermediates live in d_ws -- d_out reads are uncached/slow.)
// ---------------------------------------------------------------------------
extern "C" void kernel_launch(void* const* d_in, const int* in_sizes, int n_in,
                              void* d_out, int out_size, void* d_ws, size_t ws_size,
                              hipStream_t stream) {
  const float* z   = (const float*)d_in[0];
  const float* emb = (const float*)d_in[1];

  float* out        = (float*)d_out;
  float* out_loss   = out;
  float* out_zq     = out + 1;
  float* out_perp   = out + 4194305;
  float* out_onehot = out + 4194306;
  float* out_idx    = out + 138412034;

  float* zsq      = (float*)d_ws;            // 16384 f
  float* esq      = zsq + NROWS;             // 8192 f
  u64*   best     = (u64*)(esq + NE);        // 16384 u64
  int*   counts   = (int*)(best + NROWS);    // 8192 int
  float* partials = (float*)(counts + NE);   // 4096 f
  float* wadd     = partials + 4096;         // 16384 f
  int*   cand_n   = (int*)(wadd + NROWS);    // 1 int (+pad to 16B)
  unsigned short* ebf = (unsigned short*)(wadd + NROWS + 4); // 8192*256 bf16
  unsigned* cand  = (unsigned*)(ebf + (size_t)NE * DD);      // 4M u32

  k_rowsq<<<96, 256, 0, stream>>>(z, emb, zsq, esq, best, counts, wadd, cand_n, ebf);
  k_screen<<<1024, 256, 0, stream>>>(z, ebf, esq, wadd, cand, cand_n, out_onehot);
  k_recheck<<<512, 256, 0, stream>>>(z, emb, zsq, esq, cand, cand_n, best);
  k_gather2<<<NROWS / 4, 256, 0, stream>>>(z, emb, best, out_zq, out_onehot,
                                           out_idx, partials, counts);
  k_final<<<1, 256, 0, stream>>>(counts, partials, out_loss, out_perp);
}

// Round 13
// 952.297 us; speedup vs baseline: 1.0247x; 1.0247x over previous
//
#include <hip/hip_runtime.h>
#include <cstddef>

#define NROWS 16384
#define NE    8192
#define DD    256

typedef unsigned long long u64;
typedef float vf4 __attribute__((ext_vector_type(4)));
typedef short bf16x8 __attribute__((ext_vector_type(8)));
typedef float f32x4 __attribute__((ext_vector_type(4)));
typedef unsigned short us8 __attribute__((ext_vector_type(8)));

#define OH_TOT ((size_t)NROWS * NE)           // 134217728 floats
#define OH_VEC ((OH_TOT - 4) / 4)             // 33554431 aligned vf4 slots
#define CAND_CAP 4000000
#define LLIST_CAP 2048

// ---------------------------------------------------------------------------
// k_rowsq: zsq/esq in numpy pairwise order (bit-exact). For emb rows, ALSO
// writes ebf: bf16 emb in MFMA-fragment-major order (coalesced screen loads):
//   slot (tile*8 + kt)*64 + kq*16 + (col&15) holds eb[col][kt*32+kq*8 ..+7]
// wadd = rigorous screen window (validated rounds 6-12):
//   2*( (zsq+2)*1.2e-7 + 2*(1e-6*Ssum) + 5e-8 )
// Inits best[], counts, cand_n.
// ---------------------------------------------------------------------------
__global__ __launch_bounds__(256) void k_rowsq(
    const float* __restrict__ z, const float* __restrict__ emb,
    float* __restrict__ zsq, float* __restrict__ esq,
    u64* __restrict__ best, int* __restrict__ counts,
    float* __restrict__ wadd, int* __restrict__ cand_n,
    unsigned short* __restrict__ ebf)
{
  const int g = blockIdx.x * 256 + threadIdx.x;   // 0 .. 24575
  if (g == 0) *cand_n = 0;
  if (g < NE) counts[g] = 0;
  if (g < NROWS) best[g] = ~0ull;

  const float* row;
  float* outp;
  if (g < NROWS) { row = z + (size_t)g * DD;            outp = zsq + g; }
  else           { row = emb + (size_t)(g - NROWS) * DD; outp = esq + (g - NROWS); }

  float sa = 0.0f;
  float half_s[2];
#pragma unroll
  for (int h = 0; h < 2; ++h) {
    const float* p = row + h * 128;
    float r[8];
    {
      const float4 v0 = *(const float4*)(p);
      const float4 v1 = *(const float4*)(p + 4);
      const float xs[8] = {v0.x, v0.y, v0.z, v0.w, v1.x, v1.y, v1.z, v1.w};
#pragma unroll
      for (int j = 0; j < 8; ++j) {
        float sq = xs[j] * xs[j];
        asm volatile("" : "+v"(sq));   // np rounds x*x before the add chain
        r[j] = sq;
        sa += fabsf(xs[j]);
      }
    }
    for (int i = 8; i < 128; i += 8) {
      const float4 v0 = *(const float4*)(p + i);
      const float4 v1 = *(const float4*)(p + i + 4);
      const float xs[8] = {v0.x, v0.y, v0.z, v0.w, v1.x, v1.y, v1.z, v1.w};
#pragma unroll
      for (int j = 0; j < 8; ++j) {
        float sq = xs[j] * xs[j];
        asm volatile("" : "+v"(sq));
        r[j] = r[j] + sq;
        sa += fabsf(xs[j]);
      }
    }
    half_s[h] = ((r[0] + r[1]) + (r[2] + r[3])) + ((r[4] + r[5]) + (r[6] + r[7]));
  }
  const float zs = half_s[0] + half_s[1];
  *outp = zs;
  if (g < NROWS) {
    wadd[g] = 2.0f * ((zs + 2.0f) * 1.2e-7f + 2.0f * (1.0e-6f * sa) + 5.0e-8f);
  } else {
    const int c = g - NROWS;
    const int t = c >> 4, l = c & 15;
#pragma unroll
    for (int kt = 0; kt < 8; ++kt) {
#pragma unroll
      for (int kq = 0; kq < 4; ++kq) {
        const float4 v0 = *(const float4*)(row + kt * 32 + kq * 8);
        const float4 v1 = *(const float4*)(row + kt * 32 + kq * 8 + 4);
        const float xs[8] = {v0.x, v0.y, v0.z, v0.w, v1.x, v1.y, v1.z, v1.w};
        us8 u;
#pragma unroll
        for (int j = 0; j < 8; ++j) {
          const unsigned b = __float_as_uint(xs[j]);
          u[j] = (unsigned short)((b + 0x7FFFu + ((b >> 16) & 1u)) >> 16);
        }
        *(us8*)(ebf + (((size_t)(t * 8 + kt)) * 64 + kq * 16 + l) * 8) = u;
      }
    }
  }
}

__device__ __forceinline__ unsigned short f2bf_rne(float f) {
  const unsigned u = __float_as_uint(f);
  return (unsigned short)((u + 0x7FFFu + ((u >> 16) & 1u)) >> 16);
}
__device__ __forceinline__ unsigned encf(float f) {
  const unsigned u = __float_as_uint(f);
  return (u & 0x80000000u) ? ~u : (u | 0x80000000u);
}
__device__ __forceinline__ float decf(unsigned k) {
  const unsigned u = (k & 0x80000000u) ? (k ^ 0x80000000u) : ~k;
  return __uint_as_float(u);
}

// async global->LDS, 16 B per lane: LDS dest = uniform base + lane*16,
// global src = per-lane address (guide m97 pattern; ebf fragment-major is
// exactly this layout, so staged bits == v6's direct-load bits).
__device__ __forceinline__ void gload_lds16(const void* g, void* l) {
  __builtin_amdgcn_global_load_lds(
      (const __attribute__((address_space(1))) unsigned int*)g,
      (__attribute__((address_space(3))) unsigned int*)l, 16, 0, 0);
}

// ---------------------------------------------------------------------------
// k_screen v7: m97-style LDS-staged two-phase MFMA screen.
//   1024 blocks x 256 thr (4 waves); block = 128 rows x 1024 cols (one
//   col-eighth, XCD-aligned). B staged ONCE per block per tile into LDS via
//   global_load_lds (each wave issues 2 of the 8 1-KB frags), double-
//   buffered, one barrier per tile -- kills the 4x duplicated L2 reads and
//   the long-lived B-load registers that made v6 spill (VGPR=96).
//   Each wave: 2 persistent A-frag sets (32 rows), per tile 8 ds_read_b128
//   + 16 MFMA in 4 independent e/o chains (accumulation order identical to
//   v6 -> same bits; extra fp32 add <= |dot|*6e-8 inside window slack).
//   Phase 1: min-only sweep -> smin -> final thresholds. Phase 2: re-sweep,
//   emit rv <= thr (exact argmin col always qualifies; recheck is exact).
//   One-hot zero-fill fused as END burst (r9-validated).
//   NO waves_per_eu / launch_bounds-min (rounds 4/10: clamps into spill).
// ---------------------------------------------------------------------------
__global__ __launch_bounds__(256) void k_screen(
    const float* __restrict__ z, const unsigned short* __restrict__ ebf,
    const float* __restrict__ esq, const float* __restrict__ wadd,
    unsigned* __restrict__ cand, int* __restrict__ cand_n,
    float* __restrict__ ohbase)
{
  __shared__ __align__(16) unsigned char Bs[2][8192];   // 16 KB dbuf
  __shared__ unsigned smin[128];
  __shared__ float wl[128];
  __shared__ unsigned llist[LLIST_CAP];
  __shared__ unsigned lcnt;
  __shared__ unsigned gbase;

  const int tid = threadIdx.x;
  const int b = blockIdx.x;                 // 0..1023
  const int eighth = b & 7;                 // XCD id -> col-eighth
  const int panel = b >> 3;                 // 0..127
  const int R0 = panel * 128;
  const int C0 = eighth * 1024;
  const int T0 = C0 >> 4;                   // 64 tiles per sweep

  const int wave = tid >> 6;                // rows R0 + wave*32 .. +31
  const int lane = tid & 63;
  const int l15 = lane & 15;
  const int kg = lane >> 4;

  if (tid < 128) { smin[tid] = 0xFFFFFFFFu; wl[tid] = wadd[R0 + tid]; }
  if (tid == 0) lcnt = 0;

  // two persistent A-frag sets: rows R0+wave*32+l15 (af0) and +16 (af1)
  bf16x8 af0[8], af1[8];
  {
    const float* zp0 = z + (size_t)(R0 + wave * 32 + l15) * DD + kg * 8;
    const float* zp1 = zp0 + 16 * DD;
#pragma unroll
    for (int kt = 0; kt < 8; ++kt) {
      const float4 a0 = *(const float4*)(zp0 + kt * 32);
      const float4 a1 = *(const float4*)(zp0 + kt * 32 + 4);
      const float4 c0 = *(const float4*)(zp1 + kt * 32);
      const float4 c1 = *(const float4*)(zp1 + kt * 32 + 4);
      bf16x8 w, v;
      w[0] = (short)f2bf_rne(a0.x); w[1] = (short)f2bf_rne(a0.y);
      w[2] = (short)f2bf_rne(a0.z); w[3] = (short)f2bf_rne(a0.w);
      w[4] = (short)f2bf_rne(a1.x); w[5] = (short)f2bf_rne(a1.y);
      w[6] = (short)f2bf_rne(a1.z); w[7] = (short)f2bf_rne(a1.w);
      v[0] = (short)f2bf_rne(c0.x); v[1] = (short)f2bf_rne(c0.y);
      v[2] = (short)f2bf_rne(c0.z); v[3] = (short)f2bf_rne(c0.w);
      v[4] = (short)f2bf_rne(c1.x); v[5] = (short)f2bf_rne(c1.y);
      v[6] = (short)f2bf_rne(c1.z); v[7] = (short)f2bf_rne(c1.w);
      af0[kt] = w;
      af1[kt] = v;
    }
  }

  const int rbase = wave * 32 + kg * 4;     // af0 rows; af1 rows = rbase+16
  const unsigned char* fbyte = (const unsigned char*)ebf;

  // stage tile TT_ into buffer B_: this wave's 2 frags (wave*2, wave*2+1)
#define SSTAGE(B_, TT_)                                                     \
  {                                                                         \
    const unsigned char* gs = fbyte +                                       \
        (((size_t)((T0 + (TT_)) * 8 + wave * 2) * 64 + lane) << 4);         \
    gload_lds16(gs, &Bs[B_][(wave * 2) * 1024]);                            \
    gload_lds16(gs + 1024, &Bs[B_][(wave * 2 + 1) * 1024]);                 \
  }

#define LOADB(B_, BFR_)                                                     \
  _Pragma("unroll")                                                         \
  for (int fi = 0; fi < 8; ++fi)                                            \
    BFR_[fi] = *(const bf16x8*)&Bs[B_][fi * 1024 + lane * 16];

#define MFMA16(BFR_, E0_, O0_, E1_, O1_)                                    \
  _Pragma("unroll")                                                         \
  for (int kt = 0; kt < 8; kt += 2) {                                       \
    E0_ = __builtin_amdgcn_mfma_f32_16x16x32_bf16(af0[kt], BFR_[kt], E0_, 0, 0, 0);         \
    O0_ = __builtin_amdgcn_mfma_f32_16x16x32_bf16(af0[kt + 1], BFR_[kt + 1], O0_, 0, 0, 0); \
    E1_ = __builtin_amdgcn_mfma_f32_16x16x32_bf16(af1[kt], BFR_[kt], E1_, 0, 0, 0);         \
    O1_ = __builtin_amdgcn_mfma_f32_16x16x32_bf16(af1[kt + 1], BFR_[kt + 1], O1_, 0, 0, 0); \
  }

  // ---------------- phase 1: min-only sweep ----------------
  float rm[8];
#pragma unroll
  for (int i = 0; i < 8; ++i) rm[i] = 1e30f;

  SSTAGE(0, 0);
  __syncthreads();
#pragma unroll 1
  for (int tt = 0; tt < 64; ++tt) {
    if (tt + 1 < 64) SSTAGE((tt + 1) & 1, tt + 1);
    bf16x8 bfr[8];
    LOADB(tt & 1, bfr);
    f32x4 e0 = (f32x4){0, 0, 0, 0}, o0 = (f32x4){0, 0, 0, 0};
    f32x4 e1 = (f32x4){0, 0, 0, 0}, o1 = (f32x4){0, 0, 0, 0};
    MFMA16(bfr, e0, o0, e1, o1);
    const float ev = esq[C0 + tt * 16 + l15];
#pragma unroll
    for (int r = 0; r < 4; ++r) {
      rm[r]     = fminf(rm[r],     ev - 2.0f * (e0[r] + o0[r]));
      rm[4 + r] = fminf(rm[4 + r], ev - 2.0f * (e1[r] + o1[r]));
    }
    __syncthreads();
  }
  // flush to smin
#pragma unroll
  for (int rs = 0; rs < 2; ++rs)
#pragma unroll
    for (int r = 0; r < 4; ++r) {
      float mn = rm[rs * 4 + r];
      mn = fminf(mn, __shfl_xor(mn, 1, 16));
      mn = fminf(mn, __shfl_xor(mn, 2, 16));
      mn = fminf(mn, __shfl_xor(mn, 4, 16));
      mn = fminf(mn, __shfl_xor(mn, 8, 16));
      if (l15 == 0) atomicMin(&smin[rbase + rs * 16 + r], encf(mn));
    }
  __syncthreads();

  float thr[8];
#pragma unroll
  for (int rs = 0; rs < 2; ++rs)
#pragma unroll
    for (int r = 0; r < 4; ++r) {
      const int R = rbase + rs * 16 + r;
      thr[rs * 4 + r] = decf(smin[R]) + wl[R];
    }

#define PUSH(E_)                                                            \
  {                                                                         \
    const unsigned s_ = atomicAdd(&lcnt, 1u);                               \
    if (s_ < LLIST_CAP) llist[s_] = (E_);                                   \
    else { const int g_ = atomicAdd(cand_n, 1);                             \
           if (g_ < CAND_CAP) cand[g_] = (E_); }                            \
  }

  // ---------------- phase 2: emission sweep (final thresholds) ------------
  SSTAGE(0, 0);
  __syncthreads();
#pragma unroll 1
  for (int tt = 0; tt < 64; ++tt) {
    if (tt + 1 < 64) SSTAGE((tt + 1) & 1, tt + 1);
    bf16x8 bfr[8];
    LOADB(tt & 1, bfr);
    f32x4 e0 = (f32x4){0, 0, 0, 0}, o0 = (f32x4){0, 0, 0, 0};
    f32x4 e1 = (f32x4){0, 0, 0, 0}, o1 = (f32x4){0, 0, 0, 0};
    MFMA16(bfr, e0, o0, e1, o1);
    const int c = C0 + tt * 16 + l15;
    const float ev = esq[c];
    float rv[8];
    float gm = 1e30f;
#pragma unroll
    for (int r = 0; r < 4; ++r) {
      rv[r]     = ev - 2.0f * (e0[r] + o0[r]);
      rv[4 + r] = ev - 2.0f * (e1[r] + o1[r]);
      gm = fminf(gm, rv[r] - thr[r]);
      gm = fminf(gm, rv[4 + r] - thr[4 + r]);
    }
    if (gm <= 0.0f) {
#pragma unroll
      for (int rs = 0; rs < 2; ++rs)
#pragma unroll
        for (int r = 0; r < 4; ++r)
          if (rv[rs * 4 + r] <= thr[rs * 4 + r])
            PUSH(((unsigned)(R0 + rbase + rs * 16 + r) << 13) | (unsigned)c);
    }
    __syncthreads();
  }

  const unsigned n = (lcnt < LLIST_CAP) ? lcnt : LLIST_CAP;
  if (tid == 0) gbase = (unsigned)atomicAdd(cand_n, (int)n);
  __syncthreads();
  for (unsigned i = tid; i < n; i += 256) {
    const unsigned g = gbase + i;
    if (g < CAND_CAP) cand[g] = llist[i];
  }

  // ---- one-hot zero-fill END burst (r9-validated placement) ----
  {
    const vf4 zz = {0.0f, 0.0f, 0.0f, 0.0f};
    float* zp = ohbase + 2;
    size_t zt = (size_t)b * 32768 + tid;
#pragma unroll 4
    for (int i = 0; i < 128; ++i) {
      if (zt < OH_VEC) __builtin_nontemporal_store(zz, (vf4*)(zp + 4 * zt));
      zt += 256;
    }
    if (b == 0 && tid == 0) { ohbase[0] = 0.0f; ohbase[1] = 0.0f; }
    if (b == 1023 && tid == 0) { ohbase[OH_TOT - 2] = 0.0f; ohbase[OH_TOT - 1] = 0.0f; }
  }
}

// ---------------------------------------------------------------------------
// k_recheck: exact fp32 chain (ascending-k fmaf, identical rounding to the
// reference) per candidate; u64-packed atomicMin -> exact argmin with
// np.argmin first-index tie-break.
// ---------------------------------------------------------------------------
__global__ __launch_bounds__(256) void k_recheck(
    const float* __restrict__ z, const float* __restrict__ emb,
    const float* __restrict__ zsq, const float* __restrict__ esq,
    const unsigned* __restrict__ cand, const int* __restrict__ cand_n,
    u64* __restrict__ best)
{
  const int n = min(*cand_n, CAND_CAP);
  for (int i = blockIdx.x * 256 + threadIdx.x; i < n; i += gridDim.x * 256) {
    const unsigned e = cand[i];
    const int row = (int)(e >> 13);
    const int col = (int)(e & (NE - 1));
    const float4* zr = (const float4*)(z + (size_t)row * DD);
    const float4* er = (const float4*)(emb + (size_t)col * DD);
    float dot = 0.0f;
#pragma unroll 8
    for (int q = 0; q < 64; ++q) {
      const float4 a = zr[q];
      const float4 b = er[q];
      dot = fmaf(a.x, b.x, dot);
      dot = fmaf(a.y, b.y, dot);
      dot = fmaf(a.z, b.z, dot);
      dot = fmaf(a.w, b.w, dot);
    }
    const float s1 = zsq[row] + esq[col];
    const float dv = s1 - 2.0f * dot;
    atomicMin(&best[row], ((u64)__float_as_uint(dv) << 32) | (unsigned)col);
  }
}

// ---------------------------------------------------------------------------
// k_gather2: 4 rows per block. z_q gather, one-hot 1.0 scatter (zeros laid
// down by k_screen's burst), float(index), counts, per-block loss partial.
// ---------------------------------------------------------------------------
__global__ __launch_bounds__(256) void k_gather2(
    const float* __restrict__ z, const float* __restrict__ emb,
    const u64* __restrict__ best,
    float* __restrict__ out_zq, float* __restrict__ out_onehot,
    float* __restrict__ out_idx, float* __restrict__ partials,
    int* __restrict__ counts)
{
  __shared__ float sred[256];
  const int row = blockIdx.x * 4 + (threadIdx.x >> 6);
  const int lane = threadIdx.x & 63;
  const int idx = (int)(unsigned)(best[row] & 0xffffffffull);
  const int k0 = lane * 4;

  const float4 e  = *(const float4*)(emb + (size_t)idx * DD + k0);
  const float4 zv = *(const float4*)(z + (size_t)row * DD + k0);
  *(float4*)(out_zq + (size_t)row * DD + k0) = e;

  const float dx = e.x - zv.x, dy = e.y - zv.y, dz = e.z - zv.z, dw = e.w - zv.w;
  sred[threadIdx.x] = dx * dx + dy * dy + dz * dz + dw * dw;

  if (lane == 0) {
    out_idx[row] = (float)idx;
    out_onehot[(size_t)row * NE + idx] = 1.0f;
    atomicAdd(&counts[idx], 1);
  }
  __syncthreads();
  for (int s = 128; s > 0; s >>= 1) {
    if (threadIdx.x < s) sred[threadIdx.x] += sred[threadIdx.x + s];
    __syncthreads();
  }
  if (threadIdx.x == 0) partials[blockIdx.x] = sred[0];
}

// ---------------------------------------------------------------------------
// k_final: loss = 1.25 * sum(partials) / (N*D); perplexity from counts.
// ---------------------------------------------------------------------------
__global__ __launch_bounds__(256) void k_final(
    const int* __restrict__ counts, const float* __restrict__ partials,
    float* __restrict__ out_loss, float* __restrict__ out_perp)
{
  __shared__ float sred[256];
  __shared__ float sl[256];
  float le = 0.0f;
  for (int e = threadIdx.x; e < NE; e += 256) {
    const float p = (float)counts[e] * (1.0f / 16384.0f);
    le += p * logf(p + 1e-10f);
  }
  float ll = 0.0f;
  for (int b = threadIdx.x; b < NROWS / 4; b += 256) ll += partials[b];
  sred[threadIdx.x] = le;
  sl[threadIdx.x] = ll;
  __syncthreads();
  for (int s = 128; s > 0; s >>= 1) {
    if (threadIdx.x < s) {
      sred[threadIdx.x] += sred[threadIdx.x + s];
      sl[threadIdx.x] += sl[threadIdx.x + s];
    }
    __syncthreads();
  }
  if (threadIdx.x == 0) {
    *out_perp = expf(-sred[0]);
    *out_loss = sl[0] * (1.25f / 4194304.0f);  // (1+beta) * sum / (N*D)
  }
}

// ---------------------------------------------------------------------------
// Output layout (float32, reference return order):
//   [0] loss | [1..4194304] z_q_st | [4194305] perplexity
//   [4194306..] one-hot | [138412034..] indices (as float)
// Workspace (floats): zsq 16K | esq 8K | best 32K | counts 8K | partials 4K |
//   wadd 16K | cand_n+pad | ebf (bf16 fragment-major, 1M floats) | cand 16MB
// (bulk intermediates live in d_ws -- d_out reads are uncached/slow.)
// ---------------------------------------------------------------------------
extern "C" void kernel_launch(void* const* d_in, const int* in_sizes, int n_in,
                              void* d_out, int out_size, void* d_ws, size_t ws_size,
                              hipStream_t stream) {
  const float* z   = (const float*)d_in[0];
  const float* emb = (const float*)d_in[1];

  float* out        = (float*)d_out;
  float* out_loss   = out;
  float* out_zq     = out + 1;
  float* out_perp   = out + 4194305;
  float* out_onehot = out + 4194306;
  float* out_idx    = out + 138412034;

  float* zsq      = (float*)d_ws;            // 16384 f
  float* esq      = zsq + NROWS;             // 8192 f
  u64*   best     = (u64*)(esq + NE);        // 16384 u64
  int*   counts   = (int*)(best + NROWS);    // 8192 int
  float* partials = (float*)(counts + NE);   // 4096 f
  float* wadd     = partials + 4096;         // 16384 f
  int*   cand_n   = (int*)(wadd + NROWS);    // 1 int (+pad to 16B)
  unsigned short* ebf = (unsigned short*)(wadd + NROWS + 4); // 8192*256 bf16
  unsigned* cand  = (unsigned*)(ebf + (size_t)NE * DD);      // 4M u32

  k_rowsq<<<96, 256, 0, stream>>>(z, emb, zsq, esq, best, counts, wadd, cand_n, ebf);
  k_screen<<<1024, 256, 0, stream>>>(z, ebf, esq, wadd, cand, cand_n, out_onehot);
  k_recheck<<<512, 256, 0, stream>>>(z, emb, zsq, esq, cand, cand_n, best);
  k_gather2<<<NROWS / 4, 256, 0, stream>>>(z, emb, best, out_zq, out_onehot,
                                           out_idx, partials, counts);
  k_final<<<1, 256, 0, stream>>>(counts, partials, out_loss, out_perp);
}